// Round 3
// baseline (181.261 us; speedup 1.0000x reference)
//
#include <hip/hip_runtime.h>
#include <math.h>

// Problem constants (match reference)
constexpr int Nn   = 8192;
constexpr int Ee   = 4096;
constexpr int DIN  = 256;
constexpr int DOUT = 128;
constexpr int NNZ  = 65536;
constexpr int EC   = 96;   // capacity: nodes per edge (deg ~ Poisson(16))
constexpr int NC   = 48;   // capacity: edges per node (deg ~ Poisson(8))

#define TEMPR 0.08838834764831845f   // 1/sqrt(128)
#define EM1   1.7182818284590452f    // e - 1

// Pair-slot layout: slot s in [0,64) holds dims L(s)=(s>>4)*32+(s&15) and
// H(s)=L(s)+16 (the two columns one GEMM thread owns). All per-dim vectors
// and bf16 rows use this layout; dots/colsums are permutation-invariant;
// only k_final's output store unscrambles.

typedef __attribute__((ext_vector_type(8))) short short8;
typedef __attribute__((ext_vector_type(4))) float f32x4;

static __device__ __forceinline__ float wave_sum64(float v) {
#pragma unroll
    for (int m = 32; m; m >>= 1) v += __shfl_xor(v, m, 64);
    return v;
}
static __device__ __forceinline__ float wave_max64(float v) {
#pragma unroll
    for (int m = 32; m; m >>= 1) v = fmaxf(v, __shfl_xor(v, m, 64));
    return v;
}
static __device__ __forceinline__ short f2bf(float f) {
    union { float f; unsigned u; } v; v.f = f;
    const unsigned r = (v.u + 0x7FFFu + ((v.u >> 16) & 1u)) >> 16;
    return (short)r;
}
static __device__ __forceinline__ unsigned packbf2(float a, float b) {
    return ((unsigned)(unsigned short)f2bf(a)) |
           (((unsigned)(unsigned short)f2bf(b)) << 16);
}
static __device__ __forceinline__ float2 unpackbf2(unsigned u) {
    union { unsigned u; float f; } lo, hi;
    lo.u = u << 16; hi.u = u & 0xFFFF0000u;
    return make_float2(lo.f, hi.f);
}

// ---------------------------------------------------------------------------
// K0: prologue (also zeroes the accumulator/bitmap region -> no memset node).
// ---------------------------------------------------------------------------
__global__ __launch_bounds__(256) void k_ww3(
    const float* __restrict__ W, const float* __restrict__ W2,
    const float* __restrict__ W3, const float* __restrict__ bias,
    short* __restrict__ W2T, short* __restrict__ WWT, float* __restrict__ bW3,
    uint4* __restrict__ zb, unsigned zTot16)
{
    const int b = blockIdx.x;
    const int t = threadIdx.x;
    if (b < 32) {
        __shared__ float sW[8][128];
        const int r0 = b * 8;
        for (int i = t; i < 1024; i += 256)
            sW[i >> 7][i & 127] = W[(size_t)(r0 + (i >> 7)) * DOUT + (i & 127)];
        __syncthreads();
        const int c  = t & 127;
        const int rh = (t >> 7) * 4;
        float acc[4] = {0.f, 0.f, 0.f, 0.f};
        for (int k = 0; k < 128; ++k) {
            const float w3 = W3[(size_t)k * DOUT + c];
#pragma unroll
            for (int i = 0; i < 4; ++i) acc[i] = fmaf(sW[rh + i][k], w3, acc[i]);
        }
#pragma unroll
        for (int i = 0; i < 4; ++i)
            WWT[(size_t)c * DIN + (r0 + rh + i)] = f2bf(acc[i]);
    } else if (b < 40) {
        const int k0 = (b - 32) * 32;
        for (int i = t; i < 32 * 128; i += 256) {
            const int k = k0 + (i >> 7);
            const int n = i & 127;
            W2T[(size_t)n * DIN + k] = f2bf(W2[(size_t)k * DOUT + n]);
        }
    } else if (b == 40) {
        if (t < 128) {
            float acc = 0.f;
            for (int k = 0; k < 128; ++k)
                acc = fmaf(bias[k], W3[(size_t)k * DOUT + t], acc);
            bW3[t] = acc;
        }
    } else {
        uint4 z; z.x = z.y = z.z = z.w = 0u;
        for (unsigned i = (unsigned)(b - 41) * 256u + t; i < zTot16;
             i += 64u * 256u)
            zb[i] = z;
    }
}

// ---------------------------------------------------------------------------
// K1: MFMA GEMM  x4 = x@W2, xw = x@WW3 + bW3 -> xfb (uint2: {x4,xw} bf16
//     pairs, slot layout) + x4s (compact x4 copy) + CSR build + rowv.
// ---------------------------------------------------------------------------
__global__ __launch_bounds__(256) void k_gemm1f(
    const float* __restrict__ x, const short* __restrict__ W2T,
    const short* __restrict__ WWT, const float* __restrict__ bW3,
    const float* __restrict__ q, const int* __restrict__ hidx,
    unsigned* __restrict__ bitmap, int* __restrict__ degE, int* __restrict__ degN,
    int4* __restrict__ EST, int2* __restrict__ csrNES,
    uint2* __restrict__ xfb, unsigned* __restrict__ x4s,
    float* __restrict__ rowv)
{
    __shared__ float srow[16];
    const int t    = threadIdx.x;
    const int lane = t & 63;
    const int wv   = t >> 6;
    const int n16  = lane & 15;
    const int quad = lane >> 4;
    const int r0   = blockIdx.x * 16;
    const int n0   = wv * 32;

    // ---- CSR build ----
    const unsigned gid = blockIdx.x * 256 + t;
    if (gid < NNZ) {
        const int n = hidx[gid];
        const int e = hidx[NNZ + gid];
        const unsigned word = (unsigned)n * (unsigned)Ee + (unsigned)e;
        const unsigned bit  = 1u << (word & 31u);
        const unsigned old  = atomicOr(&bitmap[word >> 5], bit);
        if (!(old & bit)) {
            const int pe = atomicAdd(&degE[e], 1);
            if (pe < EC) {
                EST[e * EC + pe].x = n;
                const int pn = atomicAdd(&degN[n], 1);
                if (pn < NC)
                    csrNES[n * NC + pn] = make_int2(e, e * EC + pe);
            }
        }
    }

    // ---- MFMA main loop ----
    f32x4 acc4[2], accw[2];
#pragma unroll
    for (int nt = 0; nt < 2; ++nt) {
        acc4[nt] = (f32x4){0.f, 0.f, 0.f, 0.f};
        accw[nt] = (f32x4){0.f, 0.f, 0.f, 0.f};
    }
#pragma unroll
    for (int k0 = 0; k0 < DIN; k0 += 32) {
        const int kb = k0 + quad * 8;
        const float4 xa = *(const float4*)&x[(size_t)(r0 + n16) * DIN + kb];
        const float4 xb = *(const float4*)&x[(size_t)(r0 + n16) * DIN + kb + 4];
        short8 af;
        af[0] = f2bf(xa.x); af[1] = f2bf(xa.y); af[2] = f2bf(xa.z); af[3] = f2bf(xa.w);
        af[4] = f2bf(xb.x); af[5] = f2bf(xb.y); af[6] = f2bf(xb.z); af[7] = f2bf(xb.w);
#pragma unroll
        for (int nt = 0; nt < 2; ++nt) {
            const int col = n0 + nt * 16 + n16;
            const short8 b4 = *(const short8*)&W2T[(size_t)col * DIN + kb];
            const short8 bw = *(const short8*)&WWT[(size_t)col * DIN + kb];
            acc4[nt] = __builtin_amdgcn_mfma_f32_16x16x32_bf16(af, b4, acc4[nt], 0, 0, 0);
            accw[nt] = __builtin_amdgcn_mfma_f32_16x16x32_bf16(af, bw, accw[nt], 0, 0, 0);
        }
    }

    // ---- writeback (slot layout, wide stores) + rowv epilogue ----
    float bwv[2], qv[2];
#pragma unroll
    for (int nt = 0; nt < 2; ++nt) {
        const int col = n0 + nt * 16 + n16;
        bwv[nt] = bW3[col];
        qv[nt]  = q[col];
    }
    const int s = wv * 16 + n16;   // pair-slot: cols (n0+n16, n0+16+n16)
#pragma unroll
    for (int reg = 0; reg < 4; ++reg) {
        const int row = r0 + quad * 4 + reg;
        uint2 v;
        v.x = packbf2(acc4[0][reg], acc4[1][reg]);
        v.y = packbf2(accw[0][reg] + bwv[0], accw[1][reg] + bwv[1]);
        xfb[(size_t)row * 64 + s] = v;
        x4s[(size_t)row * 64 + s] = v.x;
    }
    float pr[4];
#pragma unroll
    for (int reg = 0; reg < 4; ++reg)
        pr[reg] = qv[0] * acc4[0][reg] + qv[1] * acc4[1][reg];
#pragma unroll
    for (int m = 8; m; m >>= 1) {
#pragma unroll
        for (int reg = 0; reg < 4; ++reg) pr[reg] += __shfl_xor(pr[reg], m, 64);
    }
    if (t < 16) srow[t] = 0.f;
    __syncthreads();
    if (n16 == 0) {
#pragma unroll
        for (int reg = 0; reg < 4; ++reg) atomicAdd(&srow[quad * 4 + reg], pr[reg]);
    }
    __syncthreads();
    if (t < 16) rowv[r0 + t] = srow[t] * TEMPR;
}

// ---------------------------------------------------------------------------
// K1b: low-contention colsums.  csAB[s] = {csx4.lo, csx4.hi, csxw.lo, csxw.hi}
//      (slot layout), c2g = sum_e ue(degE)^2.
// ---------------------------------------------------------------------------
__global__ __launch_bounds__(256) void k_reduxA(
    const uint2* __restrict__ xfb, const int* __restrict__ degE,
    float* __restrict__ csAB, float* __restrict__ c2g)
{
    const int t    = threadIdx.x;
    const int lane = t & 63;
    const int w    = t >> 6;
    const int b    = blockIdx.x;          // 64 blocks, 128 nodes each
    float2 a4 = {0.f, 0.f}, aw = {0.f, 0.f};
    for (int k = 0; k < 32; ++k) {
        const int n = b * 128 + w + k * 4;
        const uint2 u = xfb[(size_t)n * 64 + lane];
        const float2 fv = unpackbf2(u.x);
        const float2 tv = unpackbf2(u.y);
        a4.x += fv.x; a4.y += fv.y;
        aw.x += tv.x; aw.y += tv.y;
    }
    atomicAdd(&csAB[lane * 4 + 0], a4.x); atomicAdd(&csAB[lane * 4 + 1], a4.y);
    atomicAdd(&csAB[lane * 4 + 2], aw.x); atomicAdd(&csAB[lane * 4 + 3], aw.y);

    const int gid = b * 256 + t;          // edges 0..4095 in blocks 0..15
    if (gid < Ee) {
        const int de = min(degE[gid], EC);
        const float ue = de ? 1.0f / ((float)Nn + (float)de * EM1)
                            : 2.0f / (float)Nn;
        const float v = wave_sum64(ue * ue);
        if (lane == 0) atomicAdd(c2g, v);
    }
}

// ---------------------------------------------------------------------------
// K2: per-edge softmax1 -> EST.y(=S) + ws scatter; gathers xfb (one uint2 =
//     both x4 & xw pairs); writes e4b (att1@xw) and GG.x (att1@x4).
// ---------------------------------------------------------------------------
__global__ __launch_bounds__(256) void k_edge1(
    const int* __restrict__ degE, int4* __restrict__ EST,
    const float* __restrict__ rowv, const float* __restrict__ csAB,
    const uint2* __restrict__ xfb,
    unsigned* __restrict__ e4b, uint2* __restrict__ GG,
    float* __restrict__ wsArr)
{
    __shared__ int   sN[4][EC];
    __shared__ float sS[4][EC];
    const int t    = threadIdx.x;
    const int w    = t >> 6;
    const int lane = t & 63;
    const int e    = blockIdx.x * 4 + w;
    const int deg  = min(degE[e], EC);
    const float ue = deg ? 1.0f / ((float)Nn + (float)deg * EM1) : 2.0f / (float)Nn;

    int   n0 = 0, n1 = 0;
    float r0 = -INFINITY, r1 = -INFINITY;
    if (lane < deg)      { n0 = EST[e * EC + lane].x;      r0 = rowv[n0]; }
    if (lane + 64 < deg) { n1 = EST[e * EC + lane + 64].x; r1 = rowv[n1]; }
    const float m  = wave_max64(fmaxf(r0, r1));
    const float e0 = (lane < deg)      ? expf(r0 - m) : 0.f;
    const float e1 = (lane + 64 < deg) ? expf(r1 - m) : 0.f;
    const float Z  = wave_sum64(e0 + e1);
    const float inv = deg ? 1.0f / Z : 0.f;
    const float base = EM1 * ue;
    if (lane < deg) {
        const float sv = fmaf(e0, inv, base);
        sN[w][lane] = n0; sS[w][lane] = sv;
        EST[e * EC + lane].y = __float_as_int(sv);
        atomicAdd(&wsArr[n0], ue * sv);
    }
    if (lane + 64 < deg) {
        const float sv = fmaf(e1, inv, base);
        sN[w][lane + 64] = n1; sS[w][lane + 64] = sv;
        EST[e * EC + lane + 64].y = __float_as_int(sv);
        atomicAdd(&wsArr[n1], ue * sv);
    }

    const float4 cs = *(const float4*)&csAB[lane * 4];
    float2 aE = make_float2(ue * cs.z, ue * cs.w);   // xw colsum
    float2 aG = make_float2(ue * cs.x, ue * cs.y);   // x4 colsum
    int j = 0;
    for (; j + 16 <= deg; j += 16) {
        int ai[16]; float bi[16]; uint2 fu[16];
#pragma unroll
        for (int k = 0; k < 16; ++k) { ai[k] = sN[w][j+k]; bi[k] = sS[w][j+k]; }
#pragma unroll
        for (int k = 0; k < 16; ++k) fu[k] = xfb[(size_t)ai[k] * 64 + lane];
#pragma unroll
        for (int k = 0; k < 16; ++k) {
            const float2 fv = unpackbf2(fu[k].x);
            const float2 tv = unpackbf2(fu[k].y);
            aE.x = fmaf(bi[k], tv.x, aE.x); aE.y = fmaf(bi[k], tv.y, aE.y);
            aG.x = fmaf(bi[k], fv.x, aG.x); aG.y = fmaf(bi[k], fv.y, aG.y);
        }
    }
    for (; j + 8 <= deg; j += 8) {
        int ai[8]; float bi[8]; uint2 fu[8];
#pragma unroll
        for (int k = 0; k < 8; ++k) { ai[k] = sN[w][j+k]; bi[k] = sS[w][j+k]; }
#pragma unroll
        for (int k = 0; k < 8; ++k) fu[k] = xfb[(size_t)ai[k] * 64 + lane];
#pragma unroll
        for (int k = 0; k < 8; ++k) {
            const float2 fv = unpackbf2(fu[k].x);
            const float2 tv = unpackbf2(fu[k].y);
            aE.x = fmaf(bi[k], tv.x, aE.x); aE.y = fmaf(bi[k], tv.y, aE.y);
            aG.x = fmaf(bi[k], fv.x, aG.x); aG.y = fmaf(bi[k], fv.y, aG.y);
        }
    }
    for (; j < deg; ++j) {
        const int   a = sN[w][j];
        const float b = sS[w][j];
        const uint2 u = xfb[(size_t)a * 64 + lane];
        const float2 fv = unpackbf2(u.x);
        const float2 tv = unpackbf2(u.y);
        aE.x = fmaf(b, tv.x, aE.x); aE.y = fmaf(b, tv.y, aE.y);
        aG.x = fmaf(b, fv.x, aG.x); aG.y = fmaf(b, fv.y, aG.y);
    }
    e4b[(size_t)e * 64 + lane] = packbf2(aE.x, aE.y);
    GG[(size_t)e * 64 + lane].x = packbf2(aG.x, aG.y);
}

// ---------------------------------------------------------------------------
// K3: merged. Blocks 0..63: weighted colsums (vn/tw/ws on x4s) -> vxg2/twg2/
//     wsg2. Blocks 64..: per-node softmax2 (one node per wave, 8 edge-slots x
//     8 dim-lanes) -> EST.z(=T).
// ---------------------------------------------------------------------------
__global__ __launch_bounds__(256) void k_nodeB(
    const int* __restrict__ degN, const int2* __restrict__ csrNES,
    const unsigned* __restrict__ x4s, const unsigned* __restrict__ e4b,
    const float* __restrict__ wsArr, int4* __restrict__ EST,
    float* __restrict__ vxg2, float* __restrict__ twg2, float* __restrict__ wsg2)
{
    const int t    = threadIdx.x;
    const int w    = t >> 6;
    const int lane = t & 63;
    const int b    = blockIdx.x;

    if (b < 64) {                         // ---- reduxB part ----
        float2 av = {0.f, 0.f}, at2 = {0.f, 0.f}, aw = {0.f, 0.f};
        for (int k = 0; k < 32; ++k) {
            const int n   = b * 128 + w + k * 4;
            const int deg = min(degN[n], NC);
            const float vn = deg ? 1.0f / ((float)Ee + (float)deg * EM1)
                                 : 2.0f / (float)Ee;
            const float tw = deg ? fmaf((float)deg * EM1, vn, 1.0f) : 0.f;
            const float wsn = wsArr[n];
            const float2 xv = unpackbf2(x4s[(size_t)n * 64 + lane]);
            av.x  = fmaf(vn,  xv.x, av.x);  av.y  = fmaf(vn,  xv.y, av.y);
            at2.x = fmaf(tw,  xv.x, at2.x); at2.y = fmaf(tw,  xv.y, at2.y);
            aw.x  = fmaf(wsn, xv.x, aw.x);  aw.y  = fmaf(wsn, xv.y, aw.y);
        }
        atomicAdd(&vxg2[lane*2+0], av.x);  atomicAdd(&vxg2[lane*2+1], av.y);
        atomicAdd(&twg2[lane*2+0], at2.x); atomicAdd(&twg2[lane*2+1], at2.y);
        atomicAdd(&wsg2[lane*2+0], aw.x);  atomicAdd(&wsg2[lane*2+1], aw.y);
        return;
    }

    // ---- node2 part ----
    const int es   = lane >> 3;           // edge slot within pass (0..7)
    const int dl   = lane & 7;            // dim-lane
    const int n    = (b - 64) * 4 + w;    // one node per wave
    const int deg  = min(degN[n], NC);
    if (!deg) return;                     // wave-uniform
    const float vn = 1.0f / ((float)Ee + (float)deg * EM1);

    const uint4* xr = (const uint4*)&x4s[(size_t)n * 64];
    const uint4 xua = xr[dl * 2], xub = xr[dl * 2 + 1];
    const float2 x0 = unpackbf2(xua.x), x1 = unpackbf2(xua.y),
                 x2 = unpackbf2(xua.z), x3 = unpackbf2(xua.w),
                 x4v = unpackbf2(xub.x), x5 = unpackbf2(xub.y),
                 x6 = unpackbf2(xub.z), x7 = unpackbf2(xub.w);

    float dps[6]; float exs[6]; int slots[6];
    float m = -INFINITY;
#pragma unroll
    for (int p = 0; p < 6; ++p) {
        dps[p] = -INFINITY; slots[p] = 0;
        if (p * 8 >= deg) continue;       // wave-uniform branch
        const int j = p * 8 + es;
        int ej = 0;
        if (j < deg) {
            const int2 en = csrNES[n * NC + j];
            ej = en.x; slots[p] = en.y;
        }
        const uint4* er = (const uint4*)&e4b[(size_t)ej * 64];
        const uint4 ea = er[dl * 2], eb = er[dl * 2 + 1];
        float d0 = 0.f, d1 = 0.f, d2 = 0.f, d3 = 0.f;
        { const float2 ev = unpackbf2(ea.x); d0 = fmaf(ev.x, x0.x, d0); d0 = fmaf(ev.y, x0.y, d0); }
        { const float2 ev = unpackbf2(ea.y); d1 = fmaf(ev.x, x1.x, d1); d1 = fmaf(ev.y, x1.y, d1); }
        { const float2 ev = unpackbf2(ea.z); d2 = fmaf(ev.x, x2.x, d2); d2 = fmaf(ev.y, x2.y, d2); }
        { const float2 ev = unpackbf2(ea.w); d3 = fmaf(ev.x, x3.x, d3); d3 = fmaf(ev.y, x3.y, d3); }
        { const float2 ev = unpackbf2(eb.x); d0 = fmaf(ev.x, x4v.x, d0); d0 = fmaf(ev.y, x4v.y, d0); }
        { const float2 ev = unpackbf2(eb.y); d1 = fmaf(ev.x, x5.x, d1); d1 = fmaf(ev.y, x5.y, d1); }
        { const float2 ev = unpackbf2(eb.z); d2 = fmaf(ev.x, x6.x, d2); d2 = fmaf(ev.y, x6.y, d2); }
        { const float2 ev = unpackbf2(eb.w); d3 = fmaf(ev.x, x7.x, d3); d3 = fmaf(ev.y, x7.y, d3); }
        float dot = (d0 + d1) + (d2 + d3);
        dot += __shfl_xor(dot, 1, 64);
        dot += __shfl_xor(dot, 2, 64);
        dot += __shfl_xor(dot, 4, 64);
        dot = (j < deg) ? dot * TEMPR : -INFINITY;
        dps[p] = dot;
        float mm = fmaxf(dot, __shfl_xor(dot, 8, 64));
        mm = fmaxf(mm, __shfl_xor(mm, 16, 64));
        mm = fmaxf(mm, __shfl_xor(mm, 32, 64));
        m = fmaxf(m, mm);
    }
    float Z = 0.f;
#pragma unroll
    for (int p = 0; p < 6; ++p) {
        exs[p] = 0.f;
        if (p * 8 >= deg) continue;
        const float ex = (p * 8 + es < deg) ? expf(dps[p] - m) : 0.f;
        exs[p] = ex;
        float sum = ex + __shfl_xor(ex, 8, 64);
        sum += __shfl_xor(sum, 16, 64);
        sum += __shfl_xor(sum, 32, 64);
        Z += sum;
    }
    const float invZ = 1.0f / Z;
#pragma unroll
    for (int p = 0; p < 6; ++p) {
        if (p * 8 >= deg) continue;
        if (dl == 0 && p * 8 + es < deg)
            EST[slots[p]].z = __float_as_int(fmaf(EM1, vn, exs[p] * invZ));
    }
}

// ---------------------------------------------------------------------------
// K4: per-edge: GG.y[e] = vx + sum_{n in e} T[e,n] * x4[n].  One int4 load
//     per member gives both node index (.x) and T (.z).
// ---------------------------------------------------------------------------
__global__ __launch_bounds__(256) void k_g2(
    const int* __restrict__ degE, const int4* __restrict__ EST,
    const float* __restrict__ vxg2, const unsigned* __restrict__ x4s,
    uint2* __restrict__ GG)
{
    const int t    = threadIdx.x;
    const int w    = t >> 6;
    const int lane = t & 63;
    const int e    = blockIdx.x * 4 + w;
    const int deg  = min(degE[e], EC);
    float2 acc = *(const float2*)&vxg2[lane * 2];
    int j = 0;
    for (; j + 8 <= deg; j += 8) {
        int4 st[8]; unsigned fu[8];
#pragma unroll
        for (int k = 0; k < 8; ++k) st[k] = EST[e * EC + j + k];
#pragma unroll
        for (int k = 0; k < 8; ++k)
            fu[k] = x4s[(size_t)st[k].x * 64 + lane];
#pragma unroll
        for (int k = 0; k < 8; ++k) {
            const float  bt = __int_as_float(st[k].z);
            const float2 fv = unpackbf2(fu[k]);
            acc.x = fmaf(bt, fv.x, acc.x); acc.y = fmaf(bt, fv.y, acc.y);
        }
    }
    for (; j < deg; ++j) {
        const int4 st = EST[e * EC + j];
        const float bt = __int_as_float(st.z);
        const float2 fv = unpackbf2(x4s[(size_t)st.x * 64 + lane]);
        acc.x = fmaf(bt, fv.x, acc.x); acc.y = fmaf(bt, fv.y, acc.y);
    }
    GG[(size_t)e * 64 + lane].y = packbf2(acc.x, acc.y);
}

// ---------------------------------------------------------------------------
// K5: final per-node combine + elu. Per edge: csrNES (int2) -> EST (S,T in
//     one load) + GG (G1,G2 in one load).
// ---------------------------------------------------------------------------
__global__ __launch_bounds__(256) void k_final(
    const int* __restrict__ degN, const int2* __restrict__ csrNES,
    const int4* __restrict__ EST,
    const float* __restrict__ c2g, const float* __restrict__ csAB,
    const float* __restrict__ wsg2, const float* __restrict__ vxg2,
    const float* __restrict__ twg2,
    const uint2* __restrict__ GG, float* __restrict__ out)
{
    const int t    = threadIdx.x;
    const int w    = t >> 6;
    const int lane = t & 63;
    const int n    = blockIdx.x * 4 + w;
    const int deg  = min(degN[n], NC);
    const float vn = deg ? 1.0f / ((float)Ee + (float)deg * EM1) : 2.0f / (float)Ee;
    const float c2 = *c2g;
    const float2 c4v = *(const float2*)&csAB[lane * 4];     // csx4 pair
    const float2 wsv = *(const float2*)&wsg2[lane * 2];
    const float2 vxv = *(const float2*)&vxg2[lane * 2];
    const float2 twv = *(const float2*)&twg2[lane * 2];
    float2 acc;
    acc.x = fmaf(c2, c4v.x, wsv.x) + vn * fmaf((float)Ee, vxv.x, twv.x);
    acc.y = fmaf(c2, c4v.y, wsv.y) + vn * fmaf((float)Ee, vxv.y, twv.y);
    int j = 0;
    for (; j + 8 <= deg; j += 8) {
        int2 es[8]; int4 st[8]; uint2 gg[8];
#pragma unroll
        for (int k = 0; k < 8; ++k) es[k] = csrNES[n * NC + j + k];
#pragma unroll
        for (int k = 0; k < 8; ++k) {
            st[k] = EST[es[k].y];
            gg[k] = GG[(size_t)es[k].x * 64 + lane];
        }
#pragma unroll
        for (int k = 0; k < 8; ++k) {
            const float sva = __int_as_float(st[k].y);
            const float tva = __int_as_float(st[k].z);
            const float2 g1 = unpackbf2(gg[k].x);
            const float2 g2 = unpackbf2(gg[k].y);
            acc.x = fmaf(sva, g1.x, acc.x); acc.y = fmaf(sva, g1.y, acc.y);
            acc.x = fmaf(tva, g2.x, acc.x); acc.y = fmaf(tva, g2.y, acc.y);
        }
    }
    for (; j < deg; ++j) {
        const int2 es = csrNES[n * NC + j];
        const int4 st = EST[es.y];
        const uint2 gg = GG[(size_t)es.x * 64 + lane];
        const float sva = __int_as_float(st.y);
        const float tva = __int_as_float(st.z);
        const float2 g1 = unpackbf2(gg.x);
        const float2 g2 = unpackbf2(gg.y);
        acc.x = fmaf(sva, g1.x, acc.x); acc.y = fmaf(sva, g1.y, acc.y);
        acc.x = fmaf(tva, g2.x, acc.x); acc.y = fmaf(tva, g2.y, acc.y);
    }
    acc.x = acc.x > 0.f ? acc.x : expm1f(acc.x);
    acc.y = acc.y > 0.f ? acc.y : expm1f(acc.y);
    // unscramble slot layout: slot holds dims lo and lo+16
    const int lo = ((lane >> 4) << 5) + (lane & 15);
    out[(size_t)n * DOUT + lo]      = acc.x;
    out[(size_t)n * DOUT + lo + 16] = acc.y;
}

// ---------------------------------------------------------------------------
extern "C" void kernel_launch(void* const* d_in, const int* in_sizes, int n_in,
                              void* d_out, int out_size, void* d_ws, size_t ws_size,
                              hipStream_t stream)
{
    const float* x    = (const float*)d_in[0];
    const float* W    = (const float*)d_in[1];
    const float* W2   = (const float*)d_in[2];
    const float* W3   = (const float*)d_in[3];
    const float* bias = (const float*)d_in[4];
    const float* q    = (const float*)d_in[5];
    const int*   hidx = (const int*)d_in[6];
    float* out = (float*)d_out;

    char* wsp = (char*)d_ws;
    size_t o = 0;
    auto take = [&](size_t bytes) {
        size_t r = o; o += (bytes + 255) & ~(size_t)255; return r;
    };
    // --- zero-initialized region (zeroed by k_ww3 blocks 41..104) ---
    unsigned* bitmap = (unsigned*)(wsp + take((size_t)Nn * Ee / 8));   // 4 MB
    int*   degE  = (int*)  (wsp + take((size_t)Ee * 4));
    int*   degN  = (int*)  (wsp + take((size_t)Nn * 4));
    float* wsArr = (float*)(wsp + take((size_t)Nn * 4));
    float* c2g   = (float*)(wsp + take(4));
    float* csAB  = (float*)(wsp + take(64 * 16));     // float4[64] slot layout
    float* vxg2  = (float*)(wsp + take(DOUT * 4));
    float* twg2  = (float*)(wsp + take(DOUT * 4));
    float* wsg2  = (float*)(wsp + take(DOUT * 4));
    const size_t zbytes = o;
    // --- fully-overwritten / read-where-written scratch ---
    uint2*    xfb    = (uint2*)   (wsp + take((size_t)Nn * 64 * 8));   // 4 MB
    unsigned* x4s    = (unsigned*)(wsp + take((size_t)Nn * 64 * 4));   // 2 MB
    float*    rowv   = (float*)   (wsp + take((size_t)Nn * 4));
    int4*     EST    = (int4*)    (wsp + take((size_t)Ee * EC * 16));  // 6 MB
    int2*     csrNES = (int2*)    (wsp + take((size_t)Nn * NC * 8));   // 3 MB
    unsigned* e4b    = (unsigned*)(wsp + take((size_t)Ee * 64 * 4));   // 1 MB
    uint2*    GG     = (uint2*)   (wsp + take((size_t)Ee * 64 * 8));   // 2 MB
    short*    W2T    = (short*)   (wsp + take((size_t)DOUT * DIN * 2));
    short*    WWT    = (short*)   (wsp + take((size_t)DOUT * DIN * 2));
    float*    bW3    = (float*)   (wsp + take(DOUT * 4));
    (void)ws_size; (void)in_sizes; (void)n_in; (void)out_size;

    k_ww3   <<<105,        256, 0, stream>>>(W, W2, W3, bias, W2T, WWT, bW3,
                                             (uint4*)d_ws, (unsigned)(zbytes / 16));
    k_gemm1f<<<Nn / 16,    256, 0, stream>>>(x, W2T, WWT, bW3, q, hidx,
                                             bitmap, degE, degN, EST, csrNES,
                                             xfb, x4s, rowv);
    k_reduxA<<<64,         256, 0, stream>>>(xfb, degE, csAB, c2g);
    k_edge1 <<<Ee / 4,     256, 0, stream>>>(degE, EST, rowv, csAB, xfb,
                                             e4b, GG, wsArr);
    k_nodeB <<<64 + Nn/4,  256, 0, stream>>>(degN, csrNES, x4s, e4b, wsArr,
                                             EST, vxg2, twg2, wsg2);
    k_g2    <<<Ee / 4,     256, 0, stream>>>(degE, EST, vxg2, x4s, GG);
    k_final <<<Nn / 4,     256, 0, stream>>>(degN, csrNES, EST, c2g, csAB,
                                             wsg2, vxg2, twg2, GG, out);
}

// Round 4
// 164.221 us; speedup vs baseline: 1.1038x; 1.1038x over previous
//
#include <hip/hip_runtime.h>
#include <math.h>

// Problem constants (match reference)
constexpr int Nn   = 8192;
constexpr int Ee   = 4096;
constexpr int DIN  = 256;
constexpr int DOUT = 128;
constexpr int NNZ  = 65536;
constexpr int EC   = 96;   // capacity: nodes per edge (deg ~ Poisson(16))
constexpr int NC   = 48;   // capacity: edges per node (deg ~ Poisson(8))

#define TEMPR 0.08838834764831845f   // 1/sqrt(128)
#define EM1   1.7182818284590452f    // e - 1

// Pair-slot layout: slot s in [0,64) holds dims L(s)=(s>>4)*32+(s&15) and
// H(s)=L(s)+16 (the two columns one GEMM thread owns). All per-dim bf16 rows
// (x4b, xwb, e4b, G1b, G2b) and per-dim fp32 vectors (csx4, csxw, vxg, twg,
// wsg) use this layout. Dots and colsums are permutation-invariant; only
// k_final's output store unscrambles.

typedef __attribute__((ext_vector_type(8))) short short8;
typedef __attribute__((ext_vector_type(4))) float f32x4;

static __device__ __forceinline__ float wave_sum64(float v) {
#pragma unroll
    for (int m = 32; m; m >>= 1) v += __shfl_xor(v, m, 64);
    return v;
}
static __device__ __forceinline__ float wave_max64(float v) {
#pragma unroll
    for (int m = 32; m; m >>= 1) v = fmaxf(v, __shfl_xor(v, m, 64));
    return v;
}
static __device__ __forceinline__ short f2bf(float f) {
    union { float f; unsigned u; } v; v.f = f;
    const unsigned r = (v.u + 0x7FFFu + ((v.u >> 16) & 1u)) >> 16;
    return (short)r;
}
static __device__ __forceinline__ unsigned packbf2(float a, float b) {
    return ((unsigned)(unsigned short)f2bf(a)) |
           (((unsigned)(unsigned short)f2bf(b)) << 16);
}
static __device__ __forceinline__ float2 unpackbf2(unsigned u) {
    union { unsigned u; float f; } lo, hi;
    lo.u = u << 16; hi.u = u & 0xFFFF0000u;
    return make_float2(lo.f, hi.f);
}

// ---------------------------------------------------------------------------
// K0: prologue (also zeroes the accumulator/bitmap region -> no memset node).
// ---------------------------------------------------------------------------
__global__ __launch_bounds__(256) void k_ww3(
    const float* __restrict__ W, const float* __restrict__ W2,
    const float* __restrict__ W3, const float* __restrict__ bias,
    short* __restrict__ W2T, short* __restrict__ WWT, float* __restrict__ bW3,
    uint4* __restrict__ zb, unsigned zTot16)
{
    const int b = blockIdx.x;
    const int t = threadIdx.x;
    if (b < 32) {
        __shared__ float sW[8][128];
        const int r0 = b * 8;
        for (int i = t; i < 1024; i += 256)
            sW[i >> 7][i & 127] = W[(size_t)(r0 + (i >> 7)) * DOUT + (i & 127)];
        __syncthreads();
        const int c  = t & 127;
        const int rh = (t >> 7) * 4;
        float acc[4] = {0.f, 0.f, 0.f, 0.f};
        for (int k = 0; k < 128; ++k) {
            const float w3 = W3[(size_t)k * DOUT + c];
#pragma unroll
            for (int i = 0; i < 4; ++i) acc[i] = fmaf(sW[rh + i][k], w3, acc[i]);
        }
#pragma unroll
        for (int i = 0; i < 4; ++i)
            WWT[(size_t)c * DIN + (r0 + rh + i)] = f2bf(acc[i]);
    } else if (b < 40) {
        const int k0 = (b - 32) * 32;
        for (int i = t; i < 32 * 128; i += 256) {
            const int k = k0 + (i >> 7);
            const int n = i & 127;
            W2T[(size_t)n * DIN + k] = f2bf(W2[(size_t)k * DOUT + n]);
        }
    } else if (b == 40) {
        if (t < 128) {
            float acc = 0.f;
            for (int k = 0; k < 128; ++k)
                acc = fmaf(bias[k], W3[(size_t)k * DOUT + t], acc);
            bW3[t] = acc;
        }
    } else {
        uint4 z; z.x = z.y = z.z = z.w = 0u;
        for (unsigned i = (unsigned)(b - 41) * 256u + t; i < zTot16;
             i += 64u * 256u)
            zb[i] = z;
    }
}

// ---------------------------------------------------------------------------
// K1: MFMA GEMM  x4 = x@W2, xw = x@WW3 + bW3 -> bf16 pair arrays x4b/xwb
//     (slot layout, dword stores) + CSR build + rowv epilogue.
// ---------------------------------------------------------------------------
__global__ __launch_bounds__(256) void k_gemm1f(
    const float* __restrict__ x, const short* __restrict__ W2T,
    const short* __restrict__ WWT, const float* __restrict__ bW3,
    const float* __restrict__ q, const int* __restrict__ hidx,
    unsigned* __restrict__ bitmap, int* __restrict__ degE, int* __restrict__ degN,
    int* __restrict__ csrEn, int* __restrict__ csrNe, int* __restrict__ csrNs,
    unsigned* __restrict__ x4b, unsigned* __restrict__ xwb,
    float* __restrict__ rowv)
{
    __shared__ float srow[16];
    const int t    = threadIdx.x;
    const int lane = t & 63;
    const int wv   = t >> 6;
    const int n16  = lane & 15;
    const int quad = lane >> 4;
    const int r0   = blockIdx.x * 16;
    const int n0   = wv * 32;

    // ---- CSR build ----
    const unsigned gid = blockIdx.x * 256 + t;
    if (gid < NNZ) {
        const int n = hidx[gid];
        const int e = hidx[NNZ + gid];
        const unsigned word = (unsigned)n * (unsigned)Ee + (unsigned)e;
        const unsigned bit  = 1u << (word & 31u);
        const unsigned old  = atomicOr(&bitmap[word >> 5], bit);
        if (!(old & bit)) {
            const int pe = atomicAdd(&degE[e], 1);
            if (pe < EC) {
                csrEn[e * EC + pe] = n;
                const int pn = atomicAdd(&degN[n], 1);
                if (pn < NC) {
                    csrNe[n * NC + pn] = e;
                    csrNs[n * NC + pn] = e * EC + pe;
                }
            }
        }
    }

    // ---- MFMA main loop ----
    f32x4 acc4[2], accw[2];
#pragma unroll
    for (int nt = 0; nt < 2; ++nt) {
        acc4[nt] = (f32x4){0.f, 0.f, 0.f, 0.f};
        accw[nt] = (f32x4){0.f, 0.f, 0.f, 0.f};
    }
#pragma unroll
    for (int k0 = 0; k0 < DIN; k0 += 32) {
        const int kb = k0 + quad * 8;
        const float4 xa = *(const float4*)&x[(size_t)(r0 + n16) * DIN + kb];
        const float4 xb = *(const float4*)&x[(size_t)(r0 + n16) * DIN + kb + 4];
        short8 af;
        af[0] = f2bf(xa.x); af[1] = f2bf(xa.y); af[2] = f2bf(xa.z); af[3] = f2bf(xa.w);
        af[4] = f2bf(xb.x); af[5] = f2bf(xb.y); af[6] = f2bf(xb.z); af[7] = f2bf(xb.w);
#pragma unroll
        for (int nt = 0; nt < 2; ++nt) {
            const int col = n0 + nt * 16 + n16;
            const short8 b4 = *(const short8*)&W2T[(size_t)col * DIN + kb];
            const short8 bw = *(const short8*)&WWT[(size_t)col * DIN + kb];
            acc4[nt] = __builtin_amdgcn_mfma_f32_16x16x32_bf16(af, b4, acc4[nt], 0, 0, 0);
            accw[nt] = __builtin_amdgcn_mfma_f32_16x16x32_bf16(af, bw, accw[nt], 0, 0, 0);
        }
    }

    // ---- writeback (slot layout, paired dword stores) + rowv epilogue ----
    float bwv[2], qv[2];
#pragma unroll
    for (int nt = 0; nt < 2; ++nt) {
        const int col = n0 + nt * 16 + n16;
        bwv[nt] = bW3[col];
        qv[nt]  = q[col];
    }
    const int s = wv * 16 + n16;   // pair-slot: cols (n0+n16, n0+16+n16)
#pragma unroll
    for (int reg = 0; reg < 4; ++reg) {
        const int row = r0 + quad * 4 + reg;
        x4b[(size_t)row * 64 + s] = packbf2(acc4[0][reg], acc4[1][reg]);
        xwb[(size_t)row * 64 + s] = packbf2(accw[0][reg] + bwv[0],
                                            accw[1][reg] + bwv[1]);
    }
    float pr[4];
#pragma unroll
    for (int reg = 0; reg < 4; ++reg)
        pr[reg] = qv[0] * acc4[0][reg] + qv[1] * acc4[1][reg];
#pragma unroll
    for (int m = 8; m; m >>= 1) {
#pragma unroll
        for (int reg = 0; reg < 4; ++reg) pr[reg] += __shfl_xor(pr[reg], m, 64);
    }
    if (t < 16) srow[t] = 0.f;
    __syncthreads();
    if (n16 == 0) {
#pragma unroll
        for (int reg = 0; reg < 4; ++reg) atomicAdd(&srow[quad * 4 + reg], pr[reg]);
    }
    __syncthreads();
    if (t < 16) rowv[r0 + t] = srow[t] * TEMPR;
}

// ---------------------------------------------------------------------------
// K1b: low-contention colsums (slot layout) + c2g.
// ---------------------------------------------------------------------------
__global__ __launch_bounds__(256) void k_reduxA(
    const unsigned* __restrict__ x4b, const unsigned* __restrict__ xwb,
    const int* __restrict__ degE,
    float* __restrict__ csx4, float* __restrict__ csxw, float* __restrict__ c2g)
{
    const int t    = threadIdx.x;
    const int lane = t & 63;
    const int w    = t >> 6;
    const int b    = blockIdx.x;          // 64 blocks, 128 nodes each
    float2 a4 = {0.f, 0.f}, aw = {0.f, 0.f};
    for (int k = 0; k < 32; ++k) {
        const int n = b * 128 + w + k * 4;
        const float2 fv = unpackbf2(x4b[(size_t)n * 64 + lane]);
        const float2 tv = unpackbf2(xwb[(size_t)n * 64 + lane]);
        a4.x += fv.x; a4.y += fv.y;
        aw.x += tv.x; aw.y += tv.y;
    }
    atomicAdd(&csx4[lane * 2 + 0], a4.x); atomicAdd(&csx4[lane * 2 + 1], a4.y);
    atomicAdd(&csxw[lane * 2 + 0], aw.x); atomicAdd(&csxw[lane * 2 + 1], aw.y);

    const int gid = b * 256 + t;          // edges 0..4095 in blocks 0..15
    if (gid < Ee) {
        const int de = min(degE[gid], EC);
        const float ue = de ? 1.0f / ((float)Nn + (float)de * EM1)
                            : 2.0f / (float)Nn;
        const float v = wave_sum64(ue * ue);
        if (lane == 0) atomicAdd(c2g, v);
    }
}

// ---------------------------------------------------------------------------
// K2: per-edge softmax1 -> Sval + ws scatter; bf16 gathers e4b / G1b.
//     128-thr blocks (2 edges) -> grid 2048: full CU residency (round-2's
//     1024x256 capped at 4 blocks/CU = 50% occupancy).
// ---------------------------------------------------------------------------
__global__ __launch_bounds__(128, 6) void k_edge1(
    const int* __restrict__ degE, const int* __restrict__ csrEn,
    const float* __restrict__ rowv,
    const float* __restrict__ csx4, const float* __restrict__ csxw,
    const unsigned* __restrict__ x4b, const unsigned* __restrict__ xwb,
    float* __restrict__ Sval, unsigned* __restrict__ e4b, unsigned* __restrict__ G1b,
    float* __restrict__ wsArr)
{
    __shared__ int   sN[2][EC];
    __shared__ float sS[2][EC];
    const int t    = threadIdx.x;
    const int w    = t >> 6;
    const int lane = t & 63;
    const int e    = blockIdx.x * 2 + w;
    const int deg  = min(degE[e], EC);
    const float ue = deg ? 1.0f / ((float)Nn + (float)deg * EM1) : 2.0f / (float)Nn;

    int   n0 = 0, n1 = 0;
    float r0 = -INFINITY, r1 = -INFINITY;
    if (lane < deg)      { n0 = csrEn[e * EC + lane];      r0 = rowv[n0]; }
    if (lane + 64 < deg) { n1 = csrEn[e * EC + lane + 64]; r1 = rowv[n1]; }
    const float m  = wave_max64(fmaxf(r0, r1));
    const float e0 = (lane < deg)      ? expf(r0 - m) : 0.f;
    const float e1 = (lane + 64 < deg) ? expf(r1 - m) : 0.f;
    const float Z  = wave_sum64(e0 + e1);
    const float inv = deg ? 1.0f / Z : 0.f;
    const float base = EM1 * ue;
    if (lane < deg) {
        const float sv = fmaf(e0, inv, base);
        sN[w][lane] = n0; sS[w][lane] = sv;
        Sval[e * EC + lane] = sv;
        atomicAdd(&wsArr[n0], ue * sv);
    }
    if (lane + 64 < deg) {
        const float sv = fmaf(e1, inv, base);
        sN[w][lane + 64] = n1; sS[w][lane + 64] = sv;
        Sval[e * EC + lane + 64] = sv;
        atomicAdd(&wsArr[n1], ue * sv);
    }

    const float2 cw = *(const float2*)&csxw[lane * 2];
    const float2 c4 = *(const float2*)&csx4[lane * 2];
    float2 aE = make_float2(ue * cw.x, ue * cw.y);
    float2 aG = make_float2(ue * c4.x, ue * c4.y);
    int j = 0;
    for (; j + 8 <= deg; j += 8) {
        int ai[8]; float bi[8]; unsigned tu[8], fu[8];
#pragma unroll
        for (int k = 0; k < 8; ++k) { ai[k] = sN[w][j+k]; bi[k] = sS[w][j+k]; }
#pragma unroll
        for (int k = 0; k < 8; ++k) {
            tu[k] = xwb[(size_t)ai[k] * 64 + lane];
            fu[k] = x4b[(size_t)ai[k] * 64 + lane];
        }
#pragma unroll
        for (int k = 0; k < 8; ++k) {
            const float2 tv = unpackbf2(tu[k]);
            const float2 fv = unpackbf2(fu[k]);
            aE.x = fmaf(bi[k], tv.x, aE.x); aE.y = fmaf(bi[k], tv.y, aE.y);
            aG.x = fmaf(bi[k], fv.x, aG.x); aG.y = fmaf(bi[k], fv.y, aG.y);
        }
    }
    for (; j < deg; ++j) {
        const int   a = sN[w][j];
        const float b = sS[w][j];
        const float2 tv = unpackbf2(xwb[(size_t)a * 64 + lane]);
        const float2 fv = unpackbf2(x4b[(size_t)a * 64 + lane]);
        aE.x = fmaf(b, tv.x, aE.x); aE.y = fmaf(b, tv.y, aE.y);
        aG.x = fmaf(b, fv.x, aG.x); aG.y = fmaf(b, fv.y, aG.y);
    }
    e4b[(size_t)e * 64 + lane] = packbf2(aE.x, aE.y);
    G1b[(size_t)e * 64 + lane] = packbf2(aG.x, aG.y);
}

// ---------------------------------------------------------------------------
// K3: merged. Blocks 0..63: weighted colsums (vn/tw/ws on x4b) -> vxg/twg/wsg.
//     Blocks 64..: per-node softmax2 (one node/wave, 8 edge-slots x 8
//     dim-lanes) -> Tval.
// ---------------------------------------------------------------------------
__global__ __launch_bounds__(256) void k_nodeB(
    const int* __restrict__ degN, const int* __restrict__ csrNe,
    const int* __restrict__ csrNs, const unsigned* __restrict__ x4b,
    const unsigned* __restrict__ e4b, const float* __restrict__ wsArr,
    float* __restrict__ Tval,
    float* __restrict__ vxg, float* __restrict__ twg, float* __restrict__ wsg)
{
    const int t    = threadIdx.x;
    const int w    = t >> 6;
    const int lane = t & 63;
    const int b    = blockIdx.x;

    if (b < 64) {                         // ---- reduxB part ----
        float2 av = {0.f, 0.f}, at2 = {0.f, 0.f}, aw = {0.f, 0.f};
        for (int k = 0; k < 32; ++k) {
            const int n   = b * 128 + w + k * 4;
            const int deg = min(degN[n], NC);
            const float vn = deg ? 1.0f / ((float)Ee + (float)deg * EM1)
                                 : 2.0f / (float)Ee;
            const float tw = deg ? fmaf((float)deg * EM1, vn, 1.0f) : 0.f;
            const float wsn = wsArr[n];
            const float2 xv = unpackbf2(x4b[(size_t)n * 64 + lane]);
            av.x  = fmaf(vn,  xv.x, av.x);  av.y  = fmaf(vn,  xv.y, av.y);
            at2.x = fmaf(tw,  xv.x, at2.x); at2.y = fmaf(tw,  xv.y, at2.y);
            aw.x  = fmaf(wsn, xv.x, aw.x);  aw.y  = fmaf(wsn, xv.y, aw.y);
        }
        atomicAdd(&vxg[lane*2+0], av.x);  atomicAdd(&vxg[lane*2+1], av.y);
        atomicAdd(&twg[lane*2+0], at2.x); atomicAdd(&twg[lane*2+1], at2.y);
        atomicAdd(&wsg[lane*2+0], aw.x);  atomicAdd(&wsg[lane*2+1], aw.y);
        return;
    }

    // ---- node2 part ----
    const int es   = lane >> 3;           // edge slot within pass (0..7)
    const int dl   = lane & 7;            // dim-lane
    const int n    = (b - 64) * 4 + w;    // one node per wave
    const int deg  = min(degN[n], NC);
    if (!deg) return;                     // wave-uniform
    const float vn = 1.0f / ((float)Ee + (float)deg * EM1);

    const uint4* xr = (const uint4*)&x4b[(size_t)n * 64];
    const uint4 xua = xr[dl * 2], xub = xr[dl * 2 + 1];
    const float2 x0 = unpackbf2(xua.x), x1 = unpackbf2(xua.y),
                 x2 = unpackbf2(xua.z), x3 = unpackbf2(xua.w),
                 x4v = unpackbf2(xub.x), x5 = unpackbf2(xub.y),
                 x6 = unpackbf2(xub.z), x7 = unpackbf2(xub.w);

    float dps[6]; float exs[6]; int slots[6];
    float m = -INFINITY;
#pragma unroll
    for (int p = 0; p < 6; ++p) {
        dps[p] = -INFINITY; slots[p] = 0;
        if (p * 8 >= deg) continue;       // wave-uniform branch
        const int j = p * 8 + es;
        int ej = 0;
        if (j < deg) { ej = csrNe[n * NC + j]; slots[p] = csrNs[n * NC + j]; }
        const uint4* er = (const uint4*)&e4b[(size_t)ej * 64];
        const uint4 ea = er[dl * 2], eb = er[dl * 2 + 1];
        float d0 = 0.f, d1 = 0.f, d2 = 0.f, d3 = 0.f;
        { const float2 ev = unpackbf2(ea.x); d0 = fmaf(ev.x, x0.x, d0); d0 = fmaf(ev.y, x0.y, d0); }
        { const float2 ev = unpackbf2(ea.y); d1 = fmaf(ev.x, x1.x, d1); d1 = fmaf(ev.y, x1.y, d1); }
        { const float2 ev = unpackbf2(ea.z); d2 = fmaf(ev.x, x2.x, d2); d2 = fmaf(ev.y, x2.y, d2); }
        { const float2 ev = unpackbf2(ea.w); d3 = fmaf(ev.x, x3.x, d3); d3 = fmaf(ev.y, x3.y, d3); }
        { const float2 ev = unpackbf2(eb.x); d0 = fmaf(ev.x, x4v.x, d0); d0 = fmaf(ev.y, x4v.y, d0); }
        { const float2 ev = unpackbf2(eb.y); d1 = fmaf(ev.x, x5.x, d1); d1 = fmaf(ev.y, x5.y, d1); }
        { const float2 ev = unpackbf2(eb.z); d2 = fmaf(ev.x, x6.x, d2); d2 = fmaf(ev.y, x6.y, d2); }
        { const float2 ev = unpackbf2(eb.w); d3 = fmaf(ev.x, x7.x, d3); d3 = fmaf(ev.y, x7.y, d3); }
        float dot = (d0 + d1) + (d2 + d3);
        dot += __shfl_xor(dot, 1, 64);
        dot += __shfl_xor(dot, 2, 64);
        dot += __shfl_xor(dot, 4, 64);
        dot = (j < deg) ? dot * TEMPR : -INFINITY;
        dps[p] = dot;
        float mm = fmaxf(dot, __shfl_xor(dot, 8, 64));
        mm = fmaxf(mm, __shfl_xor(mm, 16, 64));
        mm = fmaxf(mm, __shfl_xor(mm, 32, 64));
        m = fmaxf(m, mm);
    }
    float Z = 0.f;
#pragma unroll
    for (int p = 0; p < 6; ++p) {
        exs[p] = 0.f;
        if (p * 8 >= deg) continue;
        const float ex = (p * 8 + es < deg) ? expf(dps[p] - m) : 0.f;
        exs[p] = ex;
        float sum = ex + __shfl_xor(ex, 8, 64);
        sum += __shfl_xor(sum, 16, 64);
        sum += __shfl_xor(sum, 32, 64);
        Z += sum;
    }
    const float invZ = 1.0f / Z;
#pragma unroll
    for (int p = 0; p < 6; ++p) {
        if (p * 8 >= deg) continue;
        if (dl == 0 && p * 8 + es < deg)
            Tval[slots[p]] = fmaf(EM1, vn, exs[p] * invZ);
    }
}

// ---------------------------------------------------------------------------
// K4: per-edge: G2b[e] = vx + sum_{n in e} T[e,n] * x4[n].  128-thr blocks.
// ---------------------------------------------------------------------------
__global__ __launch_bounds__(128, 8) void k_g2(
    const int* __restrict__ degE, const int* __restrict__ csrEn,
    const float* __restrict__ Tval, const float* __restrict__ vxg,
    const unsigned* __restrict__ x4b, unsigned* __restrict__ G2b)
{
    const int t    = threadIdx.x;
    const int w    = t >> 6;
    const int lane = t & 63;
    const int e    = blockIdx.x * 2 + w;
    const int deg  = min(degE[e], EC);
    float2 acc = *(const float2*)&vxg[lane * 2];
    int j = 0;
    for (; j + 8 <= deg; j += 8) {
        int ai[8]; float bi[8]; unsigned fu[8];
#pragma unroll
        for (int k = 0; k < 8; ++k) { ai[k] = csrEn[e*EC+j+k]; bi[k] = Tval[e*EC+j+k]; }
#pragma unroll
        for (int k = 0; k < 8; ++k)
            fu[k] = x4b[(size_t)ai[k] * 64 + lane];
#pragma unroll
        for (int k = 0; k < 8; ++k) {
            const float2 fv = unpackbf2(fu[k]);
            acc.x = fmaf(bi[k], fv.x, acc.x); acc.y = fmaf(bi[k], fv.y, acc.y);
        }
    }
    for (; j < deg; ++j) {
        const int   a = csrEn[e*EC+j];
        const float b = Tval[e*EC+j];
        const float2 fv = unpackbf2(x4b[(size_t)a * 64 + lane]);
        acc.x = fmaf(b, fv.x, acc.x); acc.y = fmaf(b, fv.y, acc.y);
    }
    G2b[(size_t)e * 64 + lane] = packbf2(acc.x, acc.y);
}

// ---------------------------------------------------------------------------
// K5: final per-node combine + elu.  128-thr blocks; unscrambles slot layout.
// ---------------------------------------------------------------------------
__global__ __launch_bounds__(128, 6) void k_final(
    const int* __restrict__ degN, const int* __restrict__ csrNe,
    const int* __restrict__ csrNs, const float* __restrict__ Sval,
    const float* __restrict__ Tval,
    const float* __restrict__ c2g, const float* __restrict__ csx4,
    const float* __restrict__ wsg, const float* __restrict__ vxg,
    const float* __restrict__ twg,
    const unsigned* __restrict__ G1b, const unsigned* __restrict__ G2b,
    float* __restrict__ out)
{
    const int t    = threadIdx.x;
    const int w    = t >> 6;
    const int lane = t & 63;
    const int n    = blockIdx.x * 2 + w;
    const int deg  = min(degN[n], NC);
    const float vn = deg ? 1.0f / ((float)Ee + (float)deg * EM1) : 2.0f / (float)Ee;
    const float c2 = *c2g;
    const float2 c4v = *(const float2*)&csx4[lane * 2];
    const float2 wsv = *(const float2*)&wsg[lane * 2];
    const float2 vxv = *(const float2*)&vxg[lane * 2];
    const float2 twv = *(const float2*)&twg[lane * 2];
    float2 acc;
    acc.x = fmaf(c2, c4v.x, wsv.x) + vn * fmaf((float)Ee, vxv.x, twv.x);
    acc.y = fmaf(c2, c4v.y, wsv.y) + vn * fmaf((float)Ee, vxv.y, twv.y);
    int j = 0;
    for (; j + 4 <= deg; j += 4) {
        int ei[4], si[4]; float sv[4], tv[4]; unsigned g1u[4], g2u[4];
#pragma unroll
        for (int k = 0; k < 4; ++k) {
            ei[k] = csrNe[n*NC+j+k]; si[k] = csrNs[n*NC+j+k];
        }
#pragma unroll
        for (int k = 0; k < 4; ++k) {
            sv[k] = Sval[si[k]]; tv[k] = Tval[si[k]];
            g1u[k] = G1b[(size_t)ei[k] * 64 + lane];
            g2u[k] = G2b[(size_t)ei[k] * 64 + lane];
        }
#pragma unroll
        for (int k = 0; k < 4; ++k) {
            const float2 g1 = unpackbf2(g1u[k]);
            const float2 g2 = unpackbf2(g2u[k]);
            acc.x = fmaf(sv[k], g1.x, acc.x); acc.y = fmaf(sv[k], g1.y, acc.y);
            acc.x = fmaf(tv[k], g2.x, acc.x); acc.y = fmaf(tv[k], g2.y, acc.y);
        }
    }
    for (; j < deg; ++j) {
        const int ea = csrNe[n*NC+j];
        const int sa = csrNs[n*NC+j];
        const float sva = Sval[sa], tva = Tval[sa];
        const float2 g1a = unpackbf2(G1b[(size_t)ea * 64 + lane]);
        const float2 g2a = unpackbf2(G2b[(size_t)ea * 64 + lane]);
        acc.x = fmaf(sva, g1a.x, acc.x); acc.y = fmaf(sva, g1a.y, acc.y);
        acc.x = fmaf(tva, g2a.x, acc.x); acc.y = fmaf(tva, g2a.y, acc.y);
    }
    acc.x = acc.x > 0.f ? acc.x : expm1f(acc.x);
    acc.y = acc.y > 0.f ? acc.y : expm1f(acc.y);
    // unscramble slot layout: slot holds dims lo and lo+16
    const int lo = ((lane >> 4) << 5) + (lane & 15);
    out[(size_t)n * DOUT + lo]      = acc.x;
    out[(size_t)n * DOUT + lo + 16] = acc.y;
}

// ---------------------------------------------------------------------------
extern "C" void kernel_launch(void* const* d_in, const int* in_sizes, int n_in,
                              void* d_out, int out_size, void* d_ws, size_t ws_size,
                              hipStream_t stream)
{
    const float* x    = (const float*)d_in[0];
    const float* W    = (const float*)d_in[1];
    const float* W2   = (const float*)d_in[2];
    const float* W3   = (const float*)d_in[3];
    const float* bias = (const float*)d_in[4];
    const float* q    = (const float*)d_in[5];
    const int*   hidx = (const int*)d_in[6];
    float* out = (float*)d_out;

    char* wsp = (char*)d_ws;
    size_t o = 0;
    auto take = [&](size_t bytes) {
        size_t r = o; o += (bytes + 255) & ~(size_t)255; return r;
    };
    // --- zero-initialized region (zeroed by k_ww3 blocks 41..104) ---
    unsigned* bitmap = (unsigned*)(wsp + take((size_t)Nn * Ee / 8));   // 4 MB
    int*   degE  = (int*)  (wsp + take((size_t)Ee * 4));
    int*   degN  = (int*)  (wsp + take((size_t)Nn * 4));
    float* wsArr = (float*)(wsp + take((size_t)Nn * 4));
    float* c2g   = (float*)(wsp + take(4));
    float* csx4  = (float*)(wsp + take(DOUT * 4));
    float* csxw  = (float*)(wsp + take(DOUT * 4));
    float* vxg   = (float*)(wsp + take(DOUT * 4));
    float* twg   = (float*)(wsp + take(DOUT * 4));
    float* wsg   = (float*)(wsp + take(DOUT * 4));
    const size_t zbytes = o;
    // --- fully-overwritten scratch ---
    unsigned* x4b   = (unsigned*)(wsp + take((size_t)Nn * 64 * 4));   // bf16 pairs
    unsigned* xwb   = (unsigned*)(wsp + take((size_t)Nn * 64 * 4));   // bf16 pairs
    float*    rowv  = (float*)   (wsp + take((size_t)Nn * 4));
    int*      csrEn = (int*)     (wsp + take((size_t)Ee * EC * 4));
    float*    Sval  = (float*)   (wsp + take((size_t)Ee * EC * 4));
    float*    Tval  = (float*)   (wsp + take((size_t)Ee * EC * 4));
    int*      csrNe = (int*)     (wsp + take((size_t)Nn * NC * 4));
    int*      csrNs = (int*)     (wsp + take((size_t)Nn * NC * 4));
    unsigned* e4b   = (unsigned*)(wsp + take((size_t)Ee * 64 * 4));   // bf16 pairs
    unsigned* G1b   = (unsigned*)(wsp + take((size_t)Ee * 64 * 4));   // bf16 pairs
    unsigned* G2b   = (unsigned*)(wsp + take((size_t)Ee * 64 * 4));   // bf16 pairs
    short*    W2T   = (short*)   (wsp + take((size_t)DOUT * DIN * 2));
    short*    WWT   = (short*)   (wsp + take((size_t)DOUT * DIN * 2));
    float*    bW3   = (float*)   (wsp + take(DOUT * 4));
    (void)ws_size; (void)in_sizes; (void)n_in; (void)out_size;

    k_ww3   <<<105,       256, 0, stream>>>(W, W2, W3, bias, W2T, WWT, bW3,
                                            (uint4*)d_ws, (unsigned)(zbytes / 16));
    k_gemm1f<<<Nn / 16,   256, 0, stream>>>(x, W2T, WWT, bW3, q, hidx,
                                            bitmap, degE, degN, csrEn, csrNe, csrNs,
                                            x4b, xwb, rowv);
    k_reduxA<<<64,        256, 0, stream>>>(x4b, xwb, degE, csx4, csxw, c2g);
    k_edge1 <<<Ee / 2,    128, 0, stream>>>(degE, csrEn, rowv, csx4, csxw,
                                            x4b, xwb, Sval, e4b, G1b, wsArr);
    k_nodeB <<<64 + Nn/4, 256, 0, stream>>>(degN, csrNe, csrNs, x4b, e4b, wsArr,
                                            Tval, vxg, twg, wsg);
    k_g2    <<<Ee / 2,    128, 0, stream>>>(degE, csrEn, Tval, vxg, x4b, G2b);
    k_final <<<Nn / 2,    128, 0, stream>>>(degN, csrNe, csrNs, Sval, Tval,
                                            c2g, csx4, wsg, vxg, twg, G1b, G2b, out);
}